// Round 8
// baseline (138.750 us; speedup 1.0000x reference)
//
#include <hip/hip_runtime.h>
#include <math.h>

#define DIMS 160
#define PLANE (DIMS*DIMS)          // 25600
#define VOL (DIMS*PLANE)           // 4096000
#define NB 2
#define RH 7
#define RL 4
#define KH 15
#define KL 9

struct DoGW { float gl[KL]; float gh[KH]; };

// ============================ v15: two-pass, lean ============================
// R7 finding: harness re-poison fills ~60us are inside the timed loop every
// round (dur_us ~= kernels + 60); v14's kernels total ~64us (both <42us, absent
// from top-5). v15 cuts issue counts and z occupancy:
//  - ws is ONE interleaved float2 buffer {H,L}: z reads 1 stream at 8B/lane
//    (half the loads), xy stores 8B coalesced.
//  - dog_z: B_CZ 20 -> 1600 blocks (~25 waves/CU, was ~12); full-unroll march
//    renames all ring shifts.
//  - dog_xy: sRaw LDS stage deleted; xconv reads its 20-float window direct
//    from global (block set 8.8KB = L1-resident; 8000 independent blocks give
//    the TLP v12's persistent march lacked). One barrier. LDS 11.8KB.
//    yconv = 4 y-cols/thread, single 256-unit pass (15 b64 per 4 outputs).
// Numerics FMA-identical to v9/v14. Fallback to v9 if ws too small.

// ---- Pass A geometry ----
#define A_TS 32
#define A_RR 46                    // rows incl y-halo
// yconv b64 at cx*S, S mod 32 in {18,10}, gcd(.,32)=2 -> start banks even,
// <=2-way per phase = free (m136). xconv scalar writes (200q+row bank walk):
// exactly 2-way = free.
#define A_SH 50
#define A_SL 42

__global__ __launch_bounds__(256, 4)
void dog_xy(const float* __restrict__ X, float2* __restrict__ wsI, DoGW w) {
  __shared__ __align__(16) float sHx[A_TS * A_SH];    // 6400 B
  __shared__ __align__(16) float sLx[A_TS * A_SL];    // 5376 B (11.8 KB)

  const int bid = blockIdx.x;
  const int xt = bid % 5, yt = (bid / 5) % 5, zp = bid / 25;  // zp = b*160+z
  const int x0 = xt * A_TS, y0 = yt * A_TS;
  const float* P = X + (size_t)zp * PLANE;
  const int tid = threadIdx.x;
  const bool xin = (xt > 0) && (xt < 4);

  // ---- xconv: 368 units (46 rows x 8 quads), window direct from global ----
  #pragma unroll
  for (int rr = 0; rr < 2; ++rr) {
    const int u = tid + rr * 256;
    if (u < A_RR * 8) {
      const int row = u >> 3, q = u & 7;
      const int yg = min(max(y0 + row - RH, 0), DIMS - 1);
      const float* rp = P + (size_t)yg * DIMS;
      const int gx0 = x0 - 8 + 4 * q;
      float v[20];
      #pragma unroll
      for (int j = 0; j < 5; ++j) {
        const int gx = gx0 + 4 * j;
        float4 t;
        if (xin || (gx >= 0 && gx + 4 <= DIMS)) {
          t = *(const float4*)(rp + gx);
        } else {
          t.x = rp[min(max(gx + 0, 0), DIMS - 1)];
          t.y = rp[min(max(gx + 1, 0), DIMS - 1)];
          t.z = rp[min(max(gx + 2, 0), DIMS - 1)];
          t.w = rp[min(max(gx + 3, 0), DIMS - 1)];
        }
        v[4*j] = t.x; v[4*j+1] = t.y; v[4*j+2] = t.z; v[4*j+3] = t.w;
      }
      #pragma unroll
      for (int c = 0; c < 4; ++c) {              // high, K=15
        float a = 0.f;
        #pragma unroll
        for (int k = 0; k < KH; ++k) a = fmaf(w.gh[k], v[c + 1 + k], a);
        sHx[(4 * q + c) * A_SH + row] = a;
      }
      if (row >= 3 && row <= 42) {
        #pragma unroll
        for (int c = 0; c < 4; ++c) {            // low, K=9
          float a = 0.f;
          #pragma unroll
          for (int k = 0; k < KL; ++k) a = fmaf(w.gl[k], v[c + 4 + k], a);
          sLx[(4 * q + c) * A_SL + (row - 3)] = a;
        }
      }
    }
  }
  __syncthreads();

  // ---- yconv: 256 units (32 cx x 8 y-groups of 4), b64 reads, float2 store ----
  {
    const int cx = tid & 31, cy0 = 4 * (tid >> 5);
    float f[18], g[12];
    #pragma unroll
    for (int j = 0; j < 9; ++j) {                // sHx[cx][cy0 .. cy0+17]
      float2 t = *(const float2*)&sHx[cx * A_SH + cy0 + 2 * j];
      f[2*j] = t.x; f[2*j+1] = t.y;
    }
    #pragma unroll
    for (int j = 0; j < 6; ++j) {                // sLx[cx][cy0 .. cy0+11]
      float2 t = *(const float2*)&sLx[cx * A_SL + cy0 + 2 * j];
      g[2*j] = t.x; g[2*j+1] = t.y;
    }
    float2* const o = wsI + (size_t)zp * PLANE + (size_t)(y0 + cy0) * DIMS + (x0 + cx);
    #pragma unroll
    for (int c = 0; c < 4; ++c) {
      float ph = 0.f, pl = 0.f;
      #pragma unroll
      for (int j = 0; j < KH; ++j) ph = fmaf(w.gh[j], f[c + j], ph);
      #pragma unroll
      for (int j = 0; j < KL; ++j) pl = fmaf(w.gl[j], g[c + j], pl);
      o[(size_t)c * DIMS] = make_float2(ph, pl);
    }
  }
}

// ---- Pass B: z-ring march, no LDS/barriers, one interleaved float2 stream ----
#define B_CZ 20
#define B_NP (B_CZ + 2*RH)         // 34 planes marched per chunk

__global__ __launch_bounds__(256, 4)
void dog_z(const float2* __restrict__ wsI, float* __restrict__ out, DoGW w) {
  const int bid = blockIdx.x;
  const int cb = bid % 200, zc = bid / 200;
  const int col = cb * 256 + threadIdx.x;          // 0..51199 over (b, y*160+x)
  const int b = col / PLANE, rem = col % PLANE;    // rem flat -> coalesced
  const int zb = zc * B_CZ;
  const float2* __restrict__ pI = wsI + (size_t)b * VOL + rem;
  float* __restrict__ po = out + (size_t)b * VOL + rem;

  auto ld = [&](int q) -> float2 {
    const int zs = min(max(zb - RH + q, 0), DIMS - 1);
    return pI[(size_t)zs * PLANE];
  };

  float D[KH];
  #pragma unroll
  for (int i = 0; i < KH; ++i) D[i] = 0.f;

  float2 vA = ld(0), vB = ld(1);                   // depth-2 prefetch
  #pragma unroll
  for (int q = 0; q < B_NP; ++q) {                 // full unroll: shifts renamed
    float2 vC = (q + 2 < B_NP) ? ld(q + 2) : make_float2(0.f, 0.f);
    #pragma unroll
    for (int i = 0; i < KH; ++i) D[i] = fmaf(-w.gh[KH - 1 - i], vA.x, D[i]);
    #pragma unroll
    for (int i = 3; i < KL + 3; ++i) D[i] = fmaf(w.gl[KL + 2 - i], vA.y, D[i]);
    if (q >= 2 * RH) po[(size_t)(zb + q - 2 * RH) * PLANE] = D[0];
    #pragma unroll
    for (int i = 0; i < KH - 1; ++i) D[i] = D[i + 1];
    D[KH - 1] = 0.f;
    vA = vB; vB = vC;
  }
}

// ============== fallback: v9 verbatim (session-best single kernel) ==============
#define TSX 16
#define TSY 32
#define NTX (DIMS/TSX)
#define NTY (DIMS/TSY)
#define CZ 32
#define NCH (DIMS/CZ)
#define NSTEPS (CZ + 2*RH)
#define YHR (TSY + 2*RH)
#define SR 48
#define SH 50
#define SL 42
#define RAWSZ (YHR*SR)
#define XHSZ (TSX*SH)
#define XLSZ (TSX*SL)
#define NBLK (NTX*NTY*NCH*NB)

__global__ __launch_bounds__(512, 4)
void dog_fb(const float* __restrict__ X, float* __restrict__ out, DoGW w) {
  __shared__ __align__(16) float sRaw[2][RAWSZ];
  __shared__ __align__(16) float sXh[2][XHSZ];
  __shared__ __align__(16) float sXl[2][XLSZ];

  const int bid = blockIdx.x;
  const int xt = bid % NTX;
  const int yt = (bid / NTX) % NTY;
  const int zc = (bid / (NTX * NTY)) % NCH;
  const int b  = bid / (NTX * NTY * NCH);
  const int x0 = xt * TSX, y0 = yt * TSY, z0 = zc * CZ;
  const float* Xb = X + (size_t)b * VOL;
  const int tid = threadIdx.x;
  const bool xfast = (x0 >= 8) && (x0 + 24 <= DIMS);

  const bool y_on = tid < 256;
  const int cx  = tid & 15;
  const int cy0 = 2 * ((tid >> 4) & 15);
  const int hb = cx * SH + cy0;
  const int lb = cx * SL + cy0;
  float* const obase = out + (size_t)b * VOL + (size_t)(y0 + cy0) * DIMS + (x0 + cx);

  const bool x_on = (tid >= 256) && (tid < 256 + YHR * 4);
  const int xu = tid - 256;
  const int xr = xu >> 2, xq = xu & 3;

  const bool l_on = tid >= (512 - YHR * 4);
  const int lu = tid - (512 - YHR * 4);
  const int lrow = lu >> 2, lt = lu & 3;
  const int lyg = min(max(y0 + lrow - RH, 0), DIMS - 1);
  const int lxb = x0 - 8 + 4 * lt;

  float4 vA, vB;
  auto loadP = [&](int s) {
    const int zsrc = min(max(z0 - RH + s, 0), DIMS - 1);
    const float* rowp = Xb + ((size_t)zsrc * DIMS + lyg) * DIMS;
    if (xfast) {
      vA = *(const float4*)(rowp + lxb);
      vB = *(const float4*)(rowp + lxb + 16);
    } else {
      vA.x = rowp[min(max(lxb + 0, 0), DIMS - 1)];
      vA.y = rowp[min(max(lxb + 1, 0), DIMS - 1)];
      vA.z = rowp[min(max(lxb + 2, 0), DIMS - 1)];
      vA.w = rowp[min(max(lxb + 3, 0), DIMS - 1)];
      vB.x = rowp[min(max(lxb + 16, 0), DIMS - 1)];
      vB.y = rowp[min(max(lxb + 17, 0), DIMS - 1)];
      vB.z = rowp[min(max(lxb + 18, 0), DIMS - 1)];
      vB.w = rowp[min(max(lxb + 19, 0), DIMS - 1)];
    }
  };
  auto stageP = [&](int buf) {
    float* p = &sRaw[buf][lrow * SR + 4 * lt];
    *(float4*)(p) = vA;
    *(float4*)(p + 16) = vB;
  };

  float D0[KH], D1[KH];
  #pragma unroll
  for (int i = 0; i < KH; ++i) { D0[i] = 0.f; D1[i] = 0.f; }

  auto consumeQ = [&](int q) {
    const int qb = q & 1;
    float f[16], g[10];
    #pragma unroll
    for (int j = 0; j < 8; ++j) {
      float2 t = *(const float2*)&sXh[qb][hb + 2 * j];
      f[2 * j] = t.x; f[2 * j + 1] = t.y;
    }
    #pragma unroll
    for (int j = 0; j < 5; ++j) {
      float2 t = *(const float2*)&sXl[qb][lb + 2 * j];
      g[2 * j] = t.x; g[2 * j + 1] = t.y;
    }
    float ph0 = 0.f, ph1 = 0.f, pl0 = 0.f, pl1 = 0.f;
    #pragma unroll
    for (int j = 0; j < KH; ++j) {
      ph0 = fmaf(w.gh[j], f[j], ph0);
      ph1 = fmaf(w.gh[j], f[j + 1], ph1);
    }
    #pragma unroll
    for (int j = 0; j < KL; ++j) {
      pl0 = fmaf(w.gl[j], g[j], pl0);
      pl1 = fmaf(w.gl[j], g[j + 1], pl1);
    }
    #pragma unroll
    for (int i = 0; i < KH; ++i) {
      D0[i] = fmaf(-w.gh[KH - 1 - i], ph0, D0[i]);
      D1[i] = fmaf(-w.gh[KH - 1 - i], ph1, D1[i]);
    }
    #pragma unroll
    for (int i = 3; i < KL + 3; ++i) {
      D0[i] = fmaf(w.gl[KL + 2 - i], pl0, D0[i]);
      D1[i] = fmaf(w.gl[KL + 2 - i], pl1, D1[i]);
    }
    if (q >= 2 * RH) {
      float* op = obase + (size_t)(z0 + q - 2 * RH) * PLANE;
      op[0]    = D0[0];
      op[DIMS] = D1[0];
    }
    #pragma unroll
    for (int i = 0; i < KH - 1; ++i) { D0[i] = D0[i + 1]; D1[i] = D1[i + 1]; }
    D0[KH - 1] = 0.f; D1[KH - 1] = 0.f;
  };

  auto xconvP = [&](int cur) {
    const float* p = &sRaw[cur][xr * SR + 4 * xq];
    float v[20];
    #pragma unroll
    for (int j = 0; j < 5; ++j) {
      float4 t = *(const float4*)(p + 4 * j);
      v[4 * j] = t.x; v[4 * j + 1] = t.y; v[4 * j + 2] = t.z; v[4 * j + 3] = t.w;
    }
    #pragma unroll
    for (int c = 0; c < 4; ++c) {
      float a = 0.f;
      #pragma unroll
      for (int k = 0; k < KH; ++k) a = fmaf(w.gh[k], v[c + 1 + k], a);
      sXh[cur][(4 * xq + c) * SH + xr] = a;
    }
    if (xr >= 3 && xr <= 42) {
      #pragma unroll
      for (int c = 0; c < 4; ++c) {
        float a = 0.f;
        #pragma unroll
        for (int k = 0; k < KL; ++k) a = fmaf(w.gl[k], v[c + 4 + k], a);
        sXl[cur][(4 * xq + c) * SL + (xr - 3)] = a;
      }
    }
  };

  if (l_on) { loadP(0); stageP(0); loadP(1); }
  __syncthreads();

  #pragma unroll 5
  for (int s = 0; s < NSTEPS; ++s) {
    const int cur = s & 1;
    if (l_on) {
      if (s + 1 < NSTEPS) stageP(1 - cur);
      if (s + 2 < NSTEPS) loadP(s + 2);
    }
    if (y_on && s >= 1) consumeQ(s - 1);
    if (x_on) xconvP(cur);
    __syncthreads();
  }
  if (y_on) consumeQ(NSTEPS - 1);
}

extern "C" void kernel_launch(void* const* d_in, const int* in_sizes, int n_in,
                              void* d_out, int out_size, void* d_ws, size_t ws_size,
                              hipStream_t stream) {
  const float* X = (const float*)d_in[0];
  float* out = (float*)d_out;

  DoGW w;
  {
    double s = 0.0;
    for (int i = 0; i < KL; ++i) {
      double t = i - (KL - 1) / 2.0;
      double g = exp(-(t * t) / (2.0 * 1.0 * 1.0));
      w.gl[i] = (float)g; s += g;
    }
    for (int i = 0; i < KL; ++i) w.gl[i] = (float)((double)w.gl[i] / s);
    s = 0.0;
    for (int i = 0; i < KH; ++i) {
      double t = i - (KH - 1) / 2.0;
      double g = exp(-(t * t) / (2.0 * 1.6 * 1.6));
      w.gh[i] = (float)g; s += g;
    }
    for (int i = 0; i < KH; ++i) w.gh[i] = (float)((double)w.gh[i] / s);
  }

  const size_t need = (size_t)NB * VOL * sizeof(float2);   // 65,536,000 B
  if (ws_size >= need) {
    float2* wsI = (float2*)d_ws;
    dog_xy<<<NB * DIMS * 25, 256, 0, stream>>>(X, wsI, w);
    dog_z<<<200 * (DIMS / B_CZ), 256, 0, stream>>>(wsI, out, w);
  } else {
    dog_fb<<<NBLK, 512, 0, stream>>>(X, out, w);
  }
}

// Round 9
// 121.192 us; speedup vs baseline: 1.1449x; 1.1449x over previous
//
#include <hip/hip_runtime.h>
#include <math.h>

#define DIMS 160
#define PLANE (DIMS*DIMS)          // 25600
#define VOL (DIMS*PLANE)           // 4096000
#define NB 2
#define RH 7
#define RL 4
#define KH 15
#define KL 9

struct DoGW { float gl[KL]; float gh[KH]; };

// ============================ v16: two-pass =================================
// v15 post-mortem: dog_xy regressed to ~55us (VGPR=24 -> serialized dependent
// global loads; v12's failure mode inside pass A). v16 restores v14's staged
// dog_xy (coalesced disjoint float4 -> sRaw -> xconv b128 from LDS), KEEPING
// v15's wins: interleaved float2 ws (z reads one 8B stream) and 4-col yconv
// (15 b64 per 4 outputs). dog_z unchanged from v15 (<54us, not the bottleneck).
// Bank geometry v9-proven: b128 at 48r+4q tiles 32 banks/phase; b64 at cx*50 /
// cx*42 <=2-way = free (m136). Numerics FMA-identical. Fallback v9 kept.

// ---- Pass A geometry ----
#define A_TS 32
#define A_RR 46                    // rows incl y-halo
#define A_SRAW 48                  // raw row stride (x halo 8 each side)
#define A_SH 50
#define A_SL 42

__global__ __launch_bounds__(256, 4)
void dog_xy(const float* __restrict__ X, float2* __restrict__ wsI, DoGW w) {
  __shared__ __align__(16) float sRaw[A_RR * A_SRAW]; // 8832 B
  __shared__ __align__(16) float sHx[A_TS * A_SH];    // 6400 B
  __shared__ __align__(16) float sLx[A_TS * A_SL];    // 5376 B (20.6 KB)

  const int bid = blockIdx.x;
  const int xt = bid % 5, yt = (bid / 5) % 5, zp = bid / 25;  // zp = b*160+z
  const int x0 = xt * A_TS, y0 = yt * A_TS;
  const float* P = X + (size_t)zp * PLANE;
  const int tid = threadIdx.x;
  const bool xin = (xt > 0) && (xt < 4);

  // ---- stage raw 46x48 (x from x0-8, y clamped): 552 disjoint float4 units ----
  #pragma unroll
  for (int rr = 0; rr < 3; ++rr) {
    const int u = tid + rr * 256;
    if (u < A_RR * 12) {
      const int row = u / 12, q = u % 12;
      const int yg = min(max(y0 + row - RH, 0), DIMS - 1);
      const float* rp = P + (size_t)yg * DIMS;
      const int gx = x0 - 8 + 4 * q;
      float4 v;
      if (xin || (gx >= 0 && gx + 4 <= DIMS)) {
        v = *(const float4*)(rp + gx);
      } else {
        v.x = rp[min(max(gx + 0, 0), DIMS - 1)];
        v.y = rp[min(max(gx + 1, 0), DIMS - 1)];
        v.z = rp[min(max(gx + 2, 0), DIMS - 1)];
        v.w = rp[min(max(gx + 3, 0), DIMS - 1)];
      }
      *(float4*)&sRaw[row * A_SRAW + 4 * q] = v;     // b128: phases tile 32 banks
    }
  }
  __syncthreads();

  // ---- xconv: 368 units (46 rows x 8 quads), 20-float window from LDS ----
  #pragma unroll
  for (int rr = 0; rr < 2; ++rr) {
    const int u = tid + rr * 256;
    if (u < A_RR * 8) {
      const int row = u >> 3, q = u & 7;
      const float* p = &sRaw[row * A_SRAW + 4 * q];
      float v[20];
      #pragma unroll
      for (int j = 0; j < 5; ++j) {                  // ds_read_b128, conflict-free
        float4 t = *(const float4*)(p + 4 * j);
        v[4*j] = t.x; v[4*j+1] = t.y; v[4*j+2] = t.z; v[4*j+3] = t.w;
      }
      #pragma unroll
      for (int c = 0; c < 4; ++c) {                  // high, K=15
        float a = 0.f;
        #pragma unroll
        for (int k = 0; k < KH; ++k) a = fmaf(w.gh[k], v[c + 1 + k], a);
        sHx[(4 * q + c) * A_SH + row] = a;           // scalar write: 2-way = free
      }
      if (row >= 3 && row <= 42) {
        #pragma unroll
        for (int c = 0; c < 4; ++c) {                // low, K=9
          float a = 0.f;
          #pragma unroll
          for (int k = 0; k < KL; ++k) a = fmaf(w.gl[k], v[c + 4 + k], a);
          sLx[(4 * q + c) * A_SL + (row - 3)] = a;
        }
      }
    }
  }
  __syncthreads();

  // ---- yconv: 256 units (32 cx x 8 y-groups of 4), b64 reads, float2 store ----
  {
    const int cx = tid & 31, cy0 = 4 * (tid >> 5);
    float f[18], g[12];
    #pragma unroll
    for (int j = 0; j < 9; ++j) {                    // sHx[cx][cy0 .. cy0+17]
      float2 t = *(const float2*)&sHx[cx * A_SH + cy0 + 2 * j];
      f[2*j] = t.x; f[2*j+1] = t.y;
    }
    #pragma unroll
    for (int j = 0; j < 6; ++j) {                    // sLx[cx][cy0 .. cy0+11]
      float2 t = *(const float2*)&sLx[cx * A_SL + cy0 + 2 * j];
      g[2*j] = t.x; g[2*j+1] = t.y;
    }
    float2* const o = wsI + (size_t)zp * PLANE + (size_t)(y0 + cy0) * DIMS + (x0 + cx);
    #pragma unroll
    for (int c = 0; c < 4; ++c) {
      float ph = 0.f, pl = 0.f;
      #pragma unroll
      for (int j = 0; j < KH; ++j) ph = fmaf(w.gh[j], f[c + j], ph);
      #pragma unroll
      for (int j = 0; j < KL; ++j) pl = fmaf(w.gl[j], g[c + j], pl);
      o[(size_t)c * DIMS] = make_float2(ph, pl);
    }
  }
}

// ---- Pass B: z-ring march, no LDS/barriers, one interleaved float2 stream ----
#define B_CZ 20
#define B_NP (B_CZ + 2*RH)         // 34 planes marched per chunk

__global__ __launch_bounds__(256, 4)
void dog_z(const float2* __restrict__ wsI, float* __restrict__ out, DoGW w) {
  const int bid = blockIdx.x;
  const int cb = bid % 200, zc = bid / 200;
  const int col = cb * 256 + threadIdx.x;          // 0..51199 over (b, y*160+x)
  const int b = col / PLANE, rem = col % PLANE;    // rem flat -> coalesced
  const int zb = zc * B_CZ;
  const float2* __restrict__ pI = wsI + (size_t)b * VOL + rem;
  float* __restrict__ po = out + (size_t)b * VOL + rem;

  auto ld = [&](int q) -> float2 {
    const int zs = min(max(zb - RH + q, 0), DIMS - 1);
    return pI[(size_t)zs * PLANE];
  };

  float D[KH];
  #pragma unroll
  for (int i = 0; i < KH; ++i) D[i] = 0.f;

  float2 vA = ld(0), vB = ld(1);                   // depth-2 prefetch
  #pragma unroll
  for (int q = 0; q < B_NP; ++q) {                 // full unroll: shifts renamed
    float2 vC = (q + 2 < B_NP) ? ld(q + 2) : make_float2(0.f, 0.f);
    #pragma unroll
    for (int i = 0; i < KH; ++i) D[i] = fmaf(-w.gh[KH - 1 - i], vA.x, D[i]);
    #pragma unroll
    for (int i = 3; i < KL + 3; ++i) D[i] = fmaf(w.gl[KL + 2 - i], vA.y, D[i]);
    if (q >= 2 * RH) po[(size_t)(zb + q - 2 * RH) * PLANE] = D[0];
    #pragma unroll
    for (int i = 0; i < KH - 1; ++i) D[i] = D[i + 1];
    D[KH - 1] = 0.f;
    vA = vB; vB = vC;
  }
}

// ============== fallback: v9 verbatim (session-best single kernel) ==============
#define TSX 16
#define TSY 32
#define NTX (DIMS/TSX)
#define NTY (DIMS/TSY)
#define CZ 32
#define NCH (DIMS/CZ)
#define NSTEPS (CZ + 2*RH)
#define YHR (TSY + 2*RH)
#define SR 48
#define SH 50
#define SL 42
#define RAWSZ (YHR*SR)
#define XHSZ (TSX*SH)
#define XLSZ (TSX*SL)
#define NBLK (NTX*NTY*NCH*NB)

__global__ __launch_bounds__(512, 4)
void dog_fb(const float* __restrict__ X, float* __restrict__ out, DoGW w) {
  __shared__ __align__(16) float sRaw[2][RAWSZ];
  __shared__ __align__(16) float sXh[2][XHSZ];
  __shared__ __align__(16) float sXl[2][XLSZ];

  const int bid = blockIdx.x;
  const int xt = bid % NTX;
  const int yt = (bid / NTX) % NTY;
  const int zc = (bid / (NTX * NTY)) % NCH;
  const int b  = bid / (NTX * NTY * NCH);
  const int x0 = xt * TSX, y0 = yt * TSY, z0 = zc * CZ;
  const float* Xb = X + (size_t)b * VOL;
  const int tid = threadIdx.x;
  const bool xfast = (x0 >= 8) && (x0 + 24 <= DIMS);

  const bool y_on = tid < 256;
  const int cx  = tid & 15;
  const int cy0 = 2 * ((tid >> 4) & 15);
  const int hb = cx * SH + cy0;
  const int lb = cx * SL + cy0;
  float* const obase = out + (size_t)b * VOL + (size_t)(y0 + cy0) * DIMS + (x0 + cx);

  const bool x_on = (tid >= 256) && (tid < 256 + YHR * 4);
  const int xu = tid - 256;
  const int xr = xu >> 2, xq = xu & 3;

  const bool l_on = tid >= (512 - YHR * 4);
  const int lu = tid - (512 - YHR * 4);
  const int lrow = lu >> 2, lt = lu & 3;
  const int lyg = min(max(y0 + lrow - RH, 0), DIMS - 1);
  const int lxb = x0 - 8 + 4 * lt;

  float4 vA, vB;
  auto loadP = [&](int s) {
    const int zsrc = min(max(z0 - RH + s, 0), DIMS - 1);
    const float* rowp = Xb + ((size_t)zsrc * DIMS + lyg) * DIMS;
    if (xfast) {
      vA = *(const float4*)(rowp + lxb);
      vB = *(const float4*)(rowp + lxb + 16);
    } else {
      vA.x = rowp[min(max(lxb + 0, 0), DIMS - 1)];
      vA.y = rowp[min(max(lxb + 1, 0), DIMS - 1)];
      vA.z = rowp[min(max(lxb + 2, 0), DIMS - 1)];
      vA.w = rowp[min(max(lxb + 3, 0), DIMS - 1)];
      vB.x = rowp[min(max(lxb + 16, 0), DIMS - 1)];
      vB.y = rowp[min(max(lxb + 17, 0), DIMS - 1)];
      vB.z = rowp[min(max(lxb + 18, 0), DIMS - 1)];
      vB.w = rowp[min(max(lxb + 19, 0), DIMS - 1)];
    }
  };
  auto stageP = [&](int buf) {
    float* p = &sRaw[buf][lrow * SR + 4 * lt];
    *(float4*)(p) = vA;
    *(float4*)(p + 16) = vB;
  };

  float D0[KH], D1[KH];
  #pragma unroll
  for (int i = 0; i < KH; ++i) { D0[i] = 0.f; D1[i] = 0.f; }

  auto consumeQ = [&](int q) {
    const int qb = q & 1;
    float f[16], g[10];
    #pragma unroll
    for (int j = 0; j < 8; ++j) {
      float2 t = *(const float2*)&sXh[qb][hb + 2 * j];
      f[2 * j] = t.x; f[2 * j + 1] = t.y;
    }
    #pragma unroll
    for (int j = 0; j < 5; ++j) {
      float2 t = *(const float2*)&sXl[qb][lb + 2 * j];
      g[2 * j] = t.x; g[2 * j + 1] = t.y;
    }
    float ph0 = 0.f, ph1 = 0.f, pl0 = 0.f, pl1 = 0.f;
    #pragma unroll
    for (int j = 0; j < KH; ++j) {
      ph0 = fmaf(w.gh[j], f[j], ph0);
      ph1 = fmaf(w.gh[j], f[j + 1], ph1);
    }
    #pragma unroll
    for (int j = 0; j < KL; ++j) {
      pl0 = fmaf(w.gl[j], g[j], pl0);
      pl1 = fmaf(w.gl[j], g[j + 1], pl1);
    }
    #pragma unroll
    for (int i = 0; i < KH; ++i) {
      D0[i] = fmaf(-w.gh[KH - 1 - i], ph0, D0[i]);
      D1[i] = fmaf(-w.gh[KH - 1 - i], ph1, D1[i]);
    }
    #pragma unroll
    for (int i = 3; i < KL + 3; ++i) {
      D0[i] = fmaf(w.gl[KL + 2 - i], pl0, D0[i]);
      D1[i] = fmaf(w.gl[KL + 2 - i], pl1, D1[i]);
    }
    if (q >= 2 * RH) {
      float* op = obase + (size_t)(z0 + q - 2 * RH) * PLANE;
      op[0]    = D0[0];
      op[DIMS] = D1[0];
    }
    #pragma unroll
    for (int i = 0; i < KH - 1; ++i) { D0[i] = D0[i + 1]; D1[i] = D1[i + 1]; }
    D0[KH - 1] = 0.f; D1[KH - 1] = 0.f;
  };

  auto xconvP = [&](int cur) {
    const float* p = &sRaw[cur][xr * SR + 4 * xq];
    float v[20];
    #pragma unroll
    for (int j = 0; j < 5; ++j) {
      float4 t = *(const float4*)(p + 4 * j);
      v[4 * j] = t.x; v[4 * j + 1] = t.y; v[4 * j + 2] = t.z; v[4 * j + 3] = t.w;
    }
    #pragma unroll
    for (int c = 0; c < 4; ++c) {
      float a = 0.f;
      #pragma unroll
      for (int k = 0; k < KH; ++k) a = fmaf(w.gh[k], v[c + 1 + k], a);
      sXh[cur][(4 * xq + c) * SH + xr] = a;
    }
    if (xr >= 3 && xr <= 42) {
      #pragma unroll
      for (int c = 0; c < 4; ++c) {
        float a = 0.f;
        #pragma unroll
        for (int k = 0; k < KL; ++k) a = fmaf(w.gl[k], v[c + 4 + k], a);
        sXl[cur][(4 * xq + c) * SL + (xr - 3)] = a;
      }
    }
  };

  if (l_on) { loadP(0); stageP(0); loadP(1); }
  __syncthreads();

  #pragma unroll 5
  for (int s = 0; s < NSTEPS; ++s) {
    const int cur = s & 1;
    if (l_on) {
      if (s + 1 < NSTEPS) stageP(1 - cur);
      if (s + 2 < NSTEPS) loadP(s + 2);
    }
    if (y_on && s >= 1) consumeQ(s - 1);
    if (x_on) xconvP(cur);
    __syncthreads();
  }
  if (y_on) consumeQ(NSTEPS - 1);
}

extern "C" void kernel_launch(void* const* d_in, const int* in_sizes, int n_in,
                              void* d_out, int out_size, void* d_ws, size_t ws_size,
                              hipStream_t stream) {
  const float* X = (const float*)d_in[0];
  float* out = (float*)d_out;

  DoGW w;
  {
    double s = 0.0;
    for (int i = 0; i < KL; ++i) {
      double t = i - (KL - 1) / 2.0;
      double g = exp(-(t * t) / (2.0 * 1.0 * 1.0));
      w.gl[i] = (float)g; s += g;
    }
    for (int i = 0; i < KL; ++i) w.gl[i] = (float)((double)w.gl[i] / s);
    s = 0.0;
    for (int i = 0; i < KH; ++i) {
      double t = i - (KH - 1) / 2.0;
      double g = exp(-(t * t) / (2.0 * 1.6 * 1.6));
      w.gh[i] = (float)g; s += g;
    }
    for (int i = 0; i < KH; ++i) w.gh[i] = (float)((double)w.gh[i] / s);
  }

  const size_t need = (size_t)NB * VOL * sizeof(float2);   // 65,536,000 B
  if (ws_size >= need) {
    float2* wsI = (float2*)d_ws;
    dog_xy<<<NB * DIMS * 25, 256, 0, stream>>>(X, wsI, w);
    dog_z<<<200 * (DIMS / B_CZ), 256, 0, stream>>>(wsI, out, w);
  } else {
    dog_fb<<<NBLK, 512, 0, stream>>>(X, out, w);
  }
}